// Round 3
// baseline (13332.700 us; speedup 1.0000x reference)
//
#include <hip/hip_runtime.h>
#include <hip/hip_bf16.h>
#include <math.h>

#define BB 16
#define LL 4096
#define DD 1024
#define OD 64
#define NP 2016
#define NC 256
#define VD 64
#define NCHUNK 64
#define LCH (LL / NCHUNK)

__device__ __forceinline__ int triu_idx(int r, int c) {
  // np.triu_indices(64, k=1), row-major: idx = sum_{t<r}(63-t) + (c-r-1)
  return r * 63 - (r * (r - 1)) / 2 + (c - r - 1);
}

// ---------------- Kernel 1a: partial sums over L chunks ----------------
__global__ void k_partial(const float* __restrict__ x, float* __restrict__ partial) {
  const int b = blockIdx.y, ch = blockIdx.x, tid = threadIdx.x;
  const float4* xp = (const float4*)(x + ((size_t)b * LL + (size_t)ch * LCH) * DD) + tid;
  float4 s = make_float4(0.f, 0.f, 0.f, 0.f);
  #pragma unroll 8
  for (int l = 0; l < LCH; ++l) {
    float4 v = xp[(size_t)l * (DD / 4)];
    s.x += v.x; s.y += v.y; s.z += v.z; s.w += v.w;
  }
  ((float4*)(partial + ((size_t)(b * NCHUNK + ch)) * DD))[tid] = s;
}

// ---------------- Kernel 1b: finalize mean ----------------
__global__ void k_mean(const float* __restrict__ partial, float* __restrict__ hm) {
  const int b = blockIdx.x, tid = threadIdx.x;
  float4 s = make_float4(0.f, 0.f, 0.f, 0.f);
  for (int c = 0; c < NCHUNK; ++c) {
    float4 v = ((const float4*)(partial + ((size_t)(b * NCHUNK + c)) * DD))[tid];
    s.x += v.x; s.y += v.y; s.z += v.z; s.w += v.w;
  }
  const float inv = 1.0f / (float)LL;
  s.x *= inv; s.y *= inv; s.z *= inv; s.w *= inv;
  ((float4*)(hm + (size_t)b * DD))[tid] = s;
}

// ---------------- Kernel 2a: params = h_mean @ opw.T + opb (wave per param) ----------------
__global__ void k_params(const float* __restrict__ hm, const float* __restrict__ w,
                         const float* __restrict__ bias, float* __restrict__ params) {
  const int wave = threadIdx.x >> 6, lane = threadIdx.x & 63;
  const int p = blockIdx.x * 4 + wave;  // grid = NP/4 = 504
  float acc[BB];
  #pragma unroll
  for (int b = 0; b < BB; ++b) acc[b] = 0.f;
  const float* wr = w + (size_t)p * DD;
  for (int i = 0; i < DD; i += 64) {
    const float wv = wr[i + lane];
    #pragma unroll
    for (int b = 0; b < BB; ++b) acc[b] = fmaf(wv, hm[b * DD + i + lane], acc[b]);
  }
  #pragma unroll
  for (int b = 0; b < BB; ++b) {
    float v = acc[b];
    #pragma unroll
    for (int mk = 32; mk; mk >>= 1) v += __shfl_xor(v, mk, 64);
    if (lane == 0) params[(size_t)b * NP + p] = v + bias[p];
  }
}

// ---------------- Kernel 2b: per-batch omega -> G, VQ path, c vector ----------------
__global__ void k_perb(const float* __restrict__ hm, const float* __restrict__ params,
                       const float* __restrict__ viw, const float* __restrict__ vib,
                       const float* __restrict__ cb,
                       const float* __restrict__ oob, const float* __restrict__ vow,
                       const float* __restrict__ vob,
                       const float* __restrict__ omix_p, const float* __restrict__ vmix_p,
                       float* __restrict__ Gout, float* __restrict__ cvec) {
  const int b = blockIdx.x, tid = threadIdx.x;
  __shared__ float om[OD][OD + 1];
  __shared__ float om2[OD][OD + 1];
  __shared__ float vqi[VD];
  __shared__ float sc[NC];
  __shared__ int si[NC];
  __shared__ float cd[VD];
  __shared__ float nv_s;
  const float* par = params + (size_t)b * NP;

  for (int e2 = tid; e2 < OD * OD; e2 += 256) {
    int i = e2 >> 6, j = e2 & 63;
    float v = 0.f;
    if (i < j) v = par[triu_idx(i, j)];
    else if (i > j) v = -par[triu_idx(j, i)];
    om[i][j] = v;
  }
  __syncthreads();
  for (int e2 = tid; e2 < OD * OD; e2 += 256) {
    int i = e2 >> 6, j = e2 & 63;
    float s = 0.f;
    #pragma unroll 8
    for (int k = 0; k < OD; ++k) s = fmaf(om[i][k], om[k][j], s);
    om2[i][j] = s;
  }
  __syncthreads();
  for (int e2 = tid; e2 < OD * OD; e2 += 256) {
    int i = e2 >> 6, j = e2 & 63;
    float s3 = 0.f;
    #pragma unroll 8
    for (int k = 0; k < OD; ++k) s3 = fmaf(om2[i][k], om[k][j], s3);
    float gv = om[i][j] + 0.5f * om2[i][j] + (1.f / 6.f) * s3 + (i == j ? 1.f : 0.f);
    Gout[(size_t)b * OD * OD + e2] = gv;
  }
  // VQ input: 64-dim projection of h_mean
  if (tid < VD) {
    float a = vib[tid];
    const float* wr = viw + (size_t)tid * DD;
    const float* h = hm + (size_t)b * DD;
    #pragma unroll 8
    for (int k = 0; k < DD; ++k) a = fmaf(wr[k], h[k], a);
    vqi[tid] = a;
  }
  __syncthreads();
  if (tid == 0) {
    float s = 0.f;
    for (int k = 0; k < VD; ++k) s += vqi[k] * vqi[k];
    nv_s = fmaxf(sqrtf(s), 1e-12f);
  }
  __syncthreads();
  {
    const float* cr = cb + (size_t)tid * VD;
    float dot = 0.f, ssq = 0.f;
    #pragma unroll 8
    for (int k = 0; k < VD; ++k) { float cvv = cr[k]; dot = fmaf(cvv, vqi[k], dot); ssq = fmaf(cvv, cvv, ssq); }
    float ncn = fmaxf(sqrtf(ssq), 1e-12f);
    sc[tid] = dot / (nv_s * ncn);
    si[tid] = tid;
  }
  __syncthreads();
  for (int s = 128; s > 0; s >>= 1) {
    if (tid < s) {
      float a = sc[tid], b2 = sc[tid + s];
      int ia = si[tid], ib = si[tid + s];
      if (b2 > a || (b2 == a && ib < ia)) { sc[tid] = b2; si[tid] = ib; }
    }
    __syncthreads();
  }
  const int best = si[0];
  if (tid < VD) cd[tid] = cb[(size_t)best * VD + tid];
  __syncthreads();
  const float omix = omix_p[0], vmix = vmix_p[0];
  for (int e = tid; e < DD; e += 256) {
    float a = vob[e];
    const float* wr = vow + (size_t)e * VD;
    #pragma unroll 8
    for (int k = 0; k < VD; ++k) a = fmaf(cd[k], wr[k], a);
    cvec[(size_t)b * DD + e] = fmaf(omix, oob[e], vmix * a);
  }
}

// ---------------- Kernel 2c: M = omix * G @ oow.T  (64 x 1024 per batch) ----------------
__global__ void k_M(const float* __restrict__ G, const float* __restrict__ oow,
                    const float* __restrict__ omix_p, float* __restrict__ M) {
  const int b = blockIdx.y, eb = blockIdx.x * 64, tid = threadIdx.x;
  __shared__ float g[OD][OD];
  __shared__ float wl[64][65];
  for (int e2 = tid; e2 < OD * OD; e2 += 256) g[e2 >> 6][e2 & 63] = G[(size_t)b * OD * OD + e2];
  for (int e2 = tid; e2 < 64 * 64; e2 += 256) wl[e2 >> 6][e2 & 63] = oow[(size_t)(eb + (e2 >> 6)) * 64 + (e2 & 63)];
  __syncthreads();
  const float omix = omix_p[0];
  for (int o = tid; o < 4096; o += 256) {
    int d = o >> 6, e = o & 63;
    float s = 0.f;
    #pragma unroll
    for (int k = 0; k < 64; ++k) s = fmaf(g[d][k], wl[e][k], s);
    M[((size_t)b * OD + d) * DD + eb + e] = omix * s;
  }
}

// ---------------- Kernel 3: main pass (shared body) ----------------
// 1024 threads = one e-column each; M column (64 floats) in registers.
// Round-1/2 lesson: __launch_bounds__(1024,{4,2}) BOTH produced VGPR_Count=64
// + 19GB scratch thrash -> the 2nd arg behaves like CUDA min-BLOCKS/CU here
// ((1024,2) -> 8 waves/SIMD -> 64-VGPR cap). Use (1024,1) (cap >=128 under
// either semantics) and A/B against a no-min-bound variant.
__device__ __forceinline__ void k_main_body(const float* __restrict__ x,
                                            const float* __restrict__ M,
                                            const float* __restrict__ cvec,
                                            const float* __restrict__ nw,
                                            float* __restrict__ out,
                                            float (*xh)[OD], float (*red)[16]) {
  const int b = blockIdx.y;
  const int tbase = blockIdx.x * (LL / 16);  // 256 tokens per block
  const int e = threadIdx.x;
  const int lane = e & 63, wid = e >> 6;
  float m[OD];
  #pragma unroll
  for (int d = 0; d < OD; ++d) m[d] = M[((size_t)b * OD + d) * DD + e];
  const float ce = cvec[(size_t)b * DD + e];
  const float nwe = nw[e];
  const size_t xbase = ((size_t)b * LL + tbase) * DD;

  for (int t0 = 0; t0 < 256; t0 += 8) {
    float xv[8];
    const float* xp = x + xbase + (size_t)t0 * DD + e;
    #pragma unroll
    for (int t = 0; t < 8; ++t) xv[t] = xp[(size_t)t * DD];
    if (e < OD) {
      #pragma unroll
      for (int t = 0; t < 8; ++t) xh[t][e] = xv[t];
    }
    __syncthreads();
    #pragma unroll
    for (int t = 0; t < 8; ++t) {
      const float4* xh4 = (const float4*)xh[t];
      float r = 0.f;
      #pragma unroll
      for (int d4 = 0; d4 < 16; ++d4) {
        float4 h = xh4[d4];
        r = fmaf(h.x, m[4 * d4 + 0], r);
        r = fmaf(h.y, m[4 * d4 + 1], r);
        r = fmaf(h.z, m[4 * d4 + 2], r);
        r = fmaf(h.w, m[4 * d4 + 3], r);
      }
      xv[t] = xv[t] + r + ce;  // reuse xv as y
    }
    #pragma unroll
    for (int t = 0; t < 8; ++t) {
      float ss = xv[t] * xv[t];
      #pragma unroll
      for (int mk = 32; mk; mk >>= 1) ss += __shfl_xor(ss, mk, 64);
      if (lane == 0) red[t][wid] = ss;
    }
    __syncthreads();
    float* op = out + xbase + (size_t)t0 * DD + e;
    #pragma unroll
    for (int t = 0; t < 8; ++t) {
      float ms = 0.f;
      #pragma unroll
      for (int wv = 0; wv < 16; ++wv) ms += red[t][wv];
      const float scale = rsqrtf(ms * (1.f / (float)DD) + 1e-6f);
      op[(size_t)t * DD] = xv[t] * scale * nwe;
    }
    __syncthreads();
  }
}

__global__ __launch_bounds__(1024, 1)
void k_main_lb1(const float* __restrict__ x, const float* __restrict__ M,
                const float* __restrict__ cvec, const float* __restrict__ nw,
                float* __restrict__ out) {
  __shared__ float xh[8][OD];
  __shared__ float red[8][16];
  k_main_body(x, M, cvec, nw, out, xh, red);
}

__global__ __launch_bounds__(1024)
void k_main_nolb(const float* __restrict__ x, const float* __restrict__ M,
                 const float* __restrict__ cvec, const float* __restrict__ nw,
                 float* __restrict__ out) {
  __shared__ float xh[8][OD];
  __shared__ float red[8][16];
  k_main_body(x, M, cvec, nw, out, xh, red);
}

extern "C" void kernel_launch(void* const* d_in, const int* in_sizes, int n_in,
                              void* d_out, int out_size, void* d_ws, size_t ws_size,
                              hipStream_t stream) {
  (void)in_sizes; (void)n_in; (void)out_size; (void)ws_size;
  const float* x    = (const float*)d_in[0];
  const float* opw  = (const float*)d_in[1];
  const float* opb  = (const float*)d_in[2];
  const float* oow  = (const float*)d_in[3];
  const float* oob  = (const float*)d_in[4];
  const float* viw  = (const float*)d_in[5];
  const float* vib  = (const float*)d_in[6];
  const float* vow  = (const float*)d_in[7];
  const float* vob  = (const float*)d_in[8];
  const float* cb   = (const float*)d_in[9];
  const float* omix = (const float*)d_in[10];
  const float* vmix = (const float*)d_in[11];
  const float* nw   = (const float*)d_in[12];
  float* out = (float*)d_out;

  float* ws      = (float*)d_ws;
  float* partial = ws;                 // 16*64*1024 = 1048576
  float* hm      = ws + 1048576;       // 16384
  float* params  = ws + 1064960;       // 32256
  float* G       = ws + 1097216;       // 65536
  float* M       = ws + 1162752;       // 1048576
  float* cvec    = ws + 2211328;       // 16384  (total ~8.9 MB)

  k_partial<<<dim3(NCHUNK, BB), 256, 0, stream>>>(x, partial);
  k_mean<<<BB, 256, 0, stream>>>(partial, hm);
  k_params<<<NP / 4, 256, 0, stream>>>(hm, opw, opb, params);
  k_perb<<<BB, 256, 0, stream>>>(hm, params, viw, vib, cb, oob, vow, vob, omix, vmix, G, cvec);
  k_M<<<dim3(16, BB), 256, 0, stream>>>(G, oow, omix, M);
  // A/B: same body, two register-budget attributes; last write (nolb) is the
  // output that gets validated. rocprof per-dispatch rows give the comparison.
  k_main_lb1<<<dim3(16, BB), 1024, 0, stream>>>(x, M, cvec, nw, out);
  k_main_nolb<<<dim3(16, BB), 1024, 0, stream>>>(x, M, cvec, nw, out);
}

// Round 4
// 868.057 us; speedup vs baseline: 15.3592x; 15.3592x over previous
//
#include <hip/hip_runtime.h>
#include <hip/hip_bf16.h>
#include <math.h>

#define BB 16
#define LL 4096
#define DD 1024
#define OD 64
#define NP 2016
#define NC 256
#define VD 64
#define NCHUNK 64
#define LCH (LL / NCHUNK)
#define TOK 8

__device__ __forceinline__ int triu_idx(int r, int c) {
  return r * 63 - (r * (r - 1)) / 2 + (c - r - 1);
}

// ---------------- Kernel 1a: partial sums over L chunks ----------------
__global__ void k_partial(const float* __restrict__ x, float* __restrict__ partial) {
  const int b = blockIdx.y, ch = blockIdx.x, tid = threadIdx.x;
  const float4* xp = (const float4*)(x + ((size_t)b * LL + (size_t)ch * LCH) * DD) + tid;
  float4 s = make_float4(0.f, 0.f, 0.f, 0.f);
  #pragma unroll 8
  for (int l = 0; l < LCH; ++l) {
    float4 v = xp[(size_t)l * (DD / 4)];
    s.x += v.x; s.y += v.y; s.z += v.z; s.w += v.w;
  }
  ((float4*)(partial + ((size_t)(b * NCHUNK + ch)) * DD))[tid] = s;
}

// ---------------- Kernel 1b: finalize mean ----------------
__global__ void k_mean(const float* __restrict__ partial, float* __restrict__ hm) {
  const int b = blockIdx.x, tid = threadIdx.x;
  float4 s = make_float4(0.f, 0.f, 0.f, 0.f);
  for (int c = 0; c < NCHUNK; ++c) {
    float4 v = ((const float4*)(partial + ((size_t)(b * NCHUNK + c)) * DD))[tid];
    s.x += v.x; s.y += v.y; s.z += v.z; s.w += v.w;
  }
  const float inv = 1.0f / (float)LL;
  s.x *= inv; s.y *= inv; s.z *= inv; s.w *= inv;
  ((float4*)(hm + (size_t)b * DD))[tid] = s;
}

// ---------------- Kernel 2a: params = h_mean @ opw.T + opb ----------------
__global__ void k_params(const float* __restrict__ hm, const float* __restrict__ w,
                         const float* __restrict__ bias, float* __restrict__ params) {
  const int wave = threadIdx.x >> 6, lane = threadIdx.x & 63;
  const int p = blockIdx.x * 4 + wave;
  float acc[BB];
  #pragma unroll
  for (int b = 0; b < BB; ++b) acc[b] = 0.f;
  const float* wr = w + (size_t)p * DD;
  for (int i = 0; i < DD; i += 64) {
    const float wv = wr[i + lane];
    #pragma unroll
    for (int b = 0; b < BB; ++b) acc[b] = fmaf(wv, hm[b * DD + i + lane], acc[b]);
  }
  #pragma unroll
  for (int b = 0; b < BB; ++b) {
    float v = acc[b];
    #pragma unroll
    for (int mk = 32; mk; mk >>= 1) v += __shfl_xor(v, mk, 64);
    if (lane == 0) params[(size_t)b * NP + p] = v + bias[p];
  }
}

// ---------------- Kernel 2b: per-batch omega -> G, VQ path, c vector --------
__global__ void k_perb(const float* __restrict__ hm, const float* __restrict__ params,
                       const float* __restrict__ viw, const float* __restrict__ vib,
                       const float* __restrict__ cb,
                       const float* __restrict__ oob, const float* __restrict__ vow,
                       const float* __restrict__ vob,
                       const float* __restrict__ omix_p, const float* __restrict__ vmix_p,
                       float* __restrict__ Gout, float* __restrict__ cvec) {
  const int b = blockIdx.x, tid = threadIdx.x;
  __shared__ float om[OD][OD + 1];
  __shared__ float om2[OD][OD + 1];
  __shared__ float vqi[VD];
  __shared__ float sc[NC];
  __shared__ int si[NC];
  __shared__ float cd[VD];
  __shared__ float nv_s;
  const float* par = params + (size_t)b * NP;

  for (int e2 = tid; e2 < OD * OD; e2 += 256) {
    int i = e2 >> 6, j = e2 & 63;
    float v = 0.f;
    if (i < j) v = par[triu_idx(i, j)];
    else if (i > j) v = -par[triu_idx(j, i)];
    om[i][j] = v;
  }
  __syncthreads();
  for (int e2 = tid; e2 < OD * OD; e2 += 256) {
    int i = e2 >> 6, j = e2 & 63;
    float s = 0.f;
    #pragma unroll 8
    for (int k = 0; k < OD; ++k) s = fmaf(om[i][k], om[k][j], s);
    om2[i][j] = s;
  }
  __syncthreads();
  for (int e2 = tid; e2 < OD * OD; e2 += 256) {
    int i = e2 >> 6, j = e2 & 63;
    float s3 = 0.f;
    #pragma unroll 8
    for (int k = 0; k < OD; ++k) s3 = fmaf(om2[i][k], om[k][j], s3);
    float gv = om[i][j] + 0.5f * om2[i][j] + (1.f / 6.f) * s3 + (i == j ? 1.f : 0.f);
    Gout[(size_t)b * OD * OD + e2] = gv;
  }
  if (tid < VD) {
    float a = vib[tid];
    const float* wr = viw + (size_t)tid * DD;
    const float* h = hm + (size_t)b * DD;
    #pragma unroll 8
    for (int k = 0; k < DD; ++k) a = fmaf(wr[k], h[k], a);
    vqi[tid] = a;
  }
  __syncthreads();
  if (tid == 0) {
    float s = 0.f;
    for (int k = 0; k < VD; ++k) s += vqi[k] * vqi[k];
    nv_s = fmaxf(sqrtf(s), 1e-12f);
  }
  __syncthreads();
  {
    const float* cr = cb + (size_t)tid * VD;
    float dot = 0.f, ssq = 0.f;
    #pragma unroll 8
    for (int k = 0; k < VD; ++k) { float cvv = cr[k]; dot = fmaf(cvv, vqi[k], dot); ssq = fmaf(cvv, cvv, ssq); }
    float ncn = fmaxf(sqrtf(ssq), 1e-12f);
    sc[tid] = dot / (nv_s * ncn);
    si[tid] = tid;
  }
  __syncthreads();
  for (int s = 128; s > 0; s >>= 1) {
    if (tid < s) {
      float a = sc[tid], b2 = sc[tid + s];
      int ia = si[tid], ib = si[tid + s];
      if (b2 > a || (b2 == a && ib < ia)) { sc[tid] = b2; si[tid] = ib; }
    }
    __syncthreads();
  }
  const int best = si[0];
  if (tid < VD) cd[tid] = cb[(size_t)best * VD + tid];
  __syncthreads();
  const float omix = omix_p[0], vmix = vmix_p[0];
  for (int e = tid; e < DD; e += 256) {
    float a = vob[e];
    const float* wr = vow + (size_t)e * VD;
    #pragma unroll 8
    for (int k = 0; k < VD; ++k) a = fmaf(cd[k], wr[k], a);
    cvec[(size_t)b * DD + e] = fmaf(omix, oob[e], vmix * a);
  }
}

// ------- Kernel 2c: MT[b][e][d] = omix * sum_k G[d][k]*oow[e][k] (TRANSPOSED) ----
// Transposed layout makes each e-column's 64 M-values contiguous -> float4-loadable.
__global__ void k_MT(const float* __restrict__ G, const float* __restrict__ oow,
                     const float* __restrict__ omix_p, float* __restrict__ MT) {
  const int b = blockIdx.y, eb = blockIdx.x * 64, tid = threadIdx.x;
  __shared__ float g[OD][OD + 1];   // padded: lanes read g[d][k] with d varying
  __shared__ float wl[64][65];
  for (int e2 = tid; e2 < OD * OD; e2 += 256) g[e2 >> 6][e2 & 63] = G[(size_t)b * OD * OD + e2];
  for (int e2 = tid; e2 < 64 * 64; e2 += 256) wl[e2 >> 6][e2 & 63] = oow[(size_t)(eb + (e2 >> 6)) * 64 + (e2 & 63)];
  __syncthreads();
  const float omix = omix_p[0];
  for (int o = tid; o < 4096; o += 256) {
    int el = o >> 6, d = o & 63;   // consecutive tid -> consecutive d -> coalesced store
    float s = 0.f;
    #pragma unroll
    for (int k = 0; k < 64; ++k) s = fmaf(g[d][k], wl[el][k], s);
    MT[((size_t)b * DD + eb + el) * OD + d] = omix * s;
  }
}

// ---------------- Kernel 3: main pass ----------------
// Round-3 lesson: float m[64] NEVER promoted to registers (VGPR=64 + 19GB scratch
// under (1024,4),(1024,2),(1024,1),(1024)). Fix: float4 m4[16] from transposed MT,
// 16-iter static unrolls (SROA-friendly); x_head read via wave-uniform pointer
// (scalar-cache path) instead of LDS broadcast.
__device__ __forceinline__ void main_body_f32(const float* __restrict__ x,
                                              const float* __restrict__ MT,
                                              const float* __restrict__ cvec,
                                              const float* __restrict__ nw,
                                              float* __restrict__ out) {
  const int b = blockIdx.y;
  const int tbase = blockIdx.x * 256;
  const int e = threadIdx.x;
  const int lane = e & 63, wid = e >> 6;
  float4 m4[16];
  {
    const float4* mp = (const float4*)(MT + ((size_t)b * DD + e) * OD);
    #pragma unroll
    for (int i = 0; i < 16; ++i) m4[i] = mp[i];
  }
  const float ce = cvec[(size_t)b * DD + e];
  const float nwe = nw[e];
  __shared__ float red[TOK][16];
  __shared__ float scaleS[TOK];
  const size_t xbase = ((size_t)b * LL + tbase) * DD;

  for (int t0 = 0; t0 < 256; t0 += TOK) {
    float xv[TOK];
    const float* xp = x + xbase + (size_t)t0 * DD + e;
    #pragma unroll
    for (int t = 0; t < TOK; ++t) xv[t] = xp[(size_t)t * DD];
    #pragma unroll
    for (int t = 0; t < TOK; ++t) {
      const float* hrow = x + xbase + (size_t)(t0 + t) * DD;  // wave-uniform
      float r = 0.f;
      #pragma unroll
      for (int i = 0; i < 16; ++i) {
        const float4 h = *(const float4*)(hrow + 4 * i);
        r = fmaf(h.x, m4[i].x, r);
        r = fmaf(h.y, m4[i].y, r);
        r = fmaf(h.z, m4[i].z, r);
        r = fmaf(h.w, m4[i].w, r);
      }
      xv[t] = xv[t] + r + ce;
    }
    #pragma unroll
    for (int t = 0; t < TOK; ++t) {
      float ss = xv[t] * xv[t];
      #pragma unroll
      for (int mk = 32; mk; mk >>= 1) ss += __shfl_xor(ss, mk, 64);
      if (lane == 0) red[t][wid] = ss;
    }
    __syncthreads();
    if (e < TOK * 16) {           // waves 0-1: 16-lane group per token
      const int t = e >> 4, wv = e & 15;
      float val = red[t][wv];
      #pragma unroll
      for (int mk = 1; mk < 16; mk <<= 1) val += __shfl_xor(val, mk, 64);
      if (wv == 0) scaleS[t] = rsqrtf(val * (1.f / (float)DD) + 1e-6f);
    }
    __syncthreads();
    float* op = out + xbase + (size_t)t0 * DD + e;
    #pragma unroll
    for (int t = 0; t < TOK; ++t) op[(size_t)t * DD] = xv[t] * scaleS[t] * nwe;
    __syncthreads();
  }
}

__global__ __launch_bounds__(1024) __attribute__((amdgpu_waves_per_eu(4, 4)))
void k_main_f32(const float* __restrict__ x, const float* __restrict__ MT,
                const float* __restrict__ cvec, const float* __restrict__ nw,
                float* __restrict__ out) {
  main_body_f32(x, MT, cvec, nw, out);
}

// Insurance variant: M packed as bf16 pairs -> 32 VGPRs, survives even a 64-VGPR cap.
__global__ __launch_bounds__(1024)
void k_main_bf16(const float* __restrict__ x, const float* __restrict__ MT,
                 const float* __restrict__ cvec, const float* __restrict__ nw,
                 float* __restrict__ out) {
  const int b = blockIdx.y;
  const int tbase = blockIdx.x * 256;
  const int e = threadIdx.x;
  const int lane = e & 63, wid = e >> 6;
  unsigned int mb[32];
  {
    const float* mp = MT + ((size_t)b * DD + e) * OD;
    #pragma unroll
    for (int j = 0; j < 32; ++j) {
      unsigned int ba = __float_as_uint(mp[2 * j]);
      unsigned int bb = __float_as_uint(mp[2 * j + 1]);
      mb[j] = ((ba + 0x8000u) >> 16) | (((bb + 0x8000u) >> 16) << 16);
    }
  }
  const float ce = cvec[(size_t)b * DD + e];
  const float nwe = nw[e];
  __shared__ float red[TOK][16];
  __shared__ float scaleS[TOK];
  const size_t xbase = ((size_t)b * LL + tbase) * DD;

  for (int t0 = 0; t0 < 256; t0 += TOK) {
    float xv[TOK];
    const float* xp = x + xbase + (size_t)t0 * DD + e;
    #pragma unroll
    for (int t = 0; t < TOK; ++t) xv[t] = xp[(size_t)t * DD];
    #pragma unroll
    for (int t = 0; t < TOK; ++t) {
      const float* hrow = x + xbase + (size_t)(t0 + t) * DD;
      float r = 0.f;
      #pragma unroll
      for (int i = 0; i < 16; ++i) {
        const float4 h = *(const float4*)(hrow + 4 * i);
        unsigned int p0 = mb[2 * i], p1 = mb[2 * i + 1];
        r = fmaf(h.x, __uint_as_float(p0 << 16), r);
        r = fmaf(h.y, __uint_as_float(p0 & 0xffff0000u), r);
        r = fmaf(h.z, __uint_as_float(p1 << 16), r);
        r = fmaf(h.w, __uint_as_float(p1 & 0xffff0000u), r);
      }
      xv[t] = xv[t] + r + ce;
    }
    #pragma unroll
    for (int t = 0; t < TOK; ++t) {
      float ss = xv[t] * xv[t];
      #pragma unroll
      for (int mk = 32; mk; mk >>= 1) ss += __shfl_xor(ss, mk, 64);
      if (lane == 0) red[t][wid] = ss;
    }
    __syncthreads();
    if (e < TOK * 16) {
      const int t = e >> 4, wv = e & 15;
      float val = red[t][wv];
      #pragma unroll
      for (int mk = 1; mk < 16; mk <<= 1) val += __shfl_xor(val, mk, 64);
      if (wv == 0) scaleS[t] = rsqrtf(val * (1.f / (float)DD) + 1e-6f);
    }
    __syncthreads();
    float* op = out + xbase + (size_t)t0 * DD + e;
    #pragma unroll
    for (int t = 0; t < TOK; ++t) op[(size_t)t * DD] = xv[t] * scaleS[t] * nwe;
    __syncthreads();
  }
}

extern "C" void kernel_launch(void* const* d_in, const int* in_sizes, int n_in,
                              void* d_out, int out_size, void* d_ws, size_t ws_size,
                              hipStream_t stream) {
  (void)in_sizes; (void)n_in; (void)out_size; (void)ws_size;
  const float* x    = (const float*)d_in[0];
  const float* opw  = (const float*)d_in[1];
  const float* opb  = (const float*)d_in[2];
  const float* oow  = (const float*)d_in[3];
  const float* oob  = (const float*)d_in[4];
  const float* viw  = (const float*)d_in[5];
  const float* vib  = (const float*)d_in[6];
  const float* vow  = (const float*)d_in[7];
  const float* vob  = (const float*)d_in[8];
  const float* cb   = (const float*)d_in[9];
  const float* omix = (const float*)d_in[10];
  const float* vmix = (const float*)d_in[11];
  const float* nw   = (const float*)d_in[12];
  float* out = (float*)d_out;

  float* ws      = (float*)d_ws;
  float* partial = ws;                 // 1048576
  float* hm      = ws + 1048576;       // 16384
  float* params  = ws + 1064960;       // 32256
  float* G       = ws + 1097216;       // 65536
  float* MT      = ws + 1162752;       // 1048576 (transposed: [b][e][d])
  float* cvec    = ws + 2211328;       // 16384

  k_partial<<<dim3(NCHUNK, BB), 256, 0, stream>>>(x, partial);
  k_mean<<<BB, 256, 0, stream>>>(partial, hm);
  k_params<<<NP / 4, 256, 0, stream>>>(hm, opw, opb, params);
  k_perb<<<BB, 256, 0, stream>>>(hm, params, viw, vib, cb, oob, vow, vob, omix, vmix, G, cvec);
  k_MT<<<dim3(16, BB), 256, 0, stream>>>(G, oow, omix, MT);
  // A/B: bf16-packed-M insurance first, exact-f32 path last (validated).
  k_main_bf16<<<dim3(16, BB), 1024, 0, stream>>>(x, MT, cvec, nw, out);
  k_main_f32<<<dim3(16, BB), 1024, 0, stream>>>(x, MT, cvec, nw, out);
}

// Round 5
// 288.694 us; speedup vs baseline: 46.1829x; 3.0068x over previous
//
#include <hip/hip_runtime.h>
#include <hip/hip_bf16.h>
#include <math.h>

#define BB 16
#define LL 4096
#define DD 1024
#define OD 64
#define NP 2016
#define NC 256
#define VD 64
#define NCHUNK 64
#define LCH (LL / NCHUNK)
#define TT 16      // tokens per MFMA tile
#define TPB 128    // tokens per block

typedef __attribute__((ext_vector_type(8))) short bf16x8;
typedef __attribute__((ext_vector_type(4))) float f32x4;

__device__ __forceinline__ int triu_idx(int r, int c) {
  return r * 63 - (r * (r - 1)) / 2 + (c - r - 1);
}

__device__ __forceinline__ unsigned short f2bf(float f) {
  unsigned int u = __float_as_uint(f);
  u += 0x7fffu + ((u >> 16) & 1u);
  return (unsigned short)(u >> 16);
}

// ---------------- Kernel 1a: partial sums over L chunks ----------------
__global__ void k_partial(const float* __restrict__ x, float* __restrict__ partial) {
  const int b = blockIdx.y, ch = blockIdx.x, tid = threadIdx.x;
  const float4* xp = (const float4*)(x + ((size_t)b * LL + (size_t)ch * LCH) * DD) + tid;
  float4 s = make_float4(0.f, 0.f, 0.f, 0.f);
  #pragma unroll 8
  for (int l = 0; l < LCH; ++l) {
    float4 v = xp[(size_t)l * (DD / 4)];
    s.x += v.x; s.y += v.y; s.z += v.z; s.w += v.w;
  }
  ((float4*)(partial + ((size_t)(b * NCHUNK + ch)) * DD))[tid] = s;
}

// ---------------- Kernel 1b: finalize mean ----------------
__global__ void k_mean(const float* __restrict__ partial, float* __restrict__ hm) {
  const int b = blockIdx.x, tid = threadIdx.x;
  float4 s = make_float4(0.f, 0.f, 0.f, 0.f);
  for (int c = 0; c < NCHUNK; ++c) {
    float4 v = ((const float4*)(partial + ((size_t)(b * NCHUNK + c)) * DD))[tid];
    s.x += v.x; s.y += v.y; s.z += v.z; s.w += v.w;
  }
  const float inv = 1.0f / (float)LL;
  s.x *= inv; s.y *= inv; s.z *= inv; s.w *= inv;
  ((float4*)(hm + (size_t)b * DD))[tid] = s;
}

// ---------------- Kernel 2a: params = h_mean @ opw.T + opb ----------------
__global__ void k_params(const float* __restrict__ hm, const float* __restrict__ w,
                         const float* __restrict__ bias, float* __restrict__ params) {
  const int wave = threadIdx.x >> 6, lane = threadIdx.x & 63;
  const int p = blockIdx.x * 4 + wave;
  float acc[BB];
  #pragma unroll
  for (int b = 0; b < BB; ++b) acc[b] = 0.f;
  const float* wr = w + (size_t)p * DD;
  for (int i = 0; i < DD; i += 64) {
    const float wv = wr[i + lane];
    #pragma unroll
    for (int b = 0; b < BB; ++b) acc[b] = fmaf(wv, hm[b * DD + i + lane], acc[b]);
  }
  #pragma unroll
  for (int b = 0; b < BB; ++b) {
    float v = acc[b];
    #pragma unroll
    for (int mk = 32; mk; mk >>= 1) v += __shfl_xor(v, mk, 64);
    if (lane == 0) params[(size_t)b * NP + p] = v + bias[p];
  }
}

// ---------------- Kernel 2b: per-batch omega -> G, VQ path, c vector --------
__global__ void k_perb(const float* __restrict__ hm, const float* __restrict__ params,
                       const float* __restrict__ viw, const float* __restrict__ vib,
                       const float* __restrict__ cb,
                       const float* __restrict__ oob, const float* __restrict__ vow,
                       const float* __restrict__ vob,
                       const float* __restrict__ omix_p, const float* __restrict__ vmix_p,
                       float* __restrict__ Gout, float* __restrict__ cvec) {
  const int b = blockIdx.x, tid = threadIdx.x;
  __shared__ float om[OD][OD + 1];
  __shared__ float om2[OD][OD + 1];
  __shared__ float vqi[VD];
  __shared__ float sc[NC];
  __shared__ int si[NC];
  __shared__ float cd[VD];
  __shared__ float nv_s;
  const float* par = params + (size_t)b * NP;

  for (int e2 = tid; e2 < OD * OD; e2 += 256) {
    int i = e2 >> 6, j = e2 & 63;
    float v = 0.f;
    if (i < j) v = par[triu_idx(i, j)];
    else if (i > j) v = -par[triu_idx(j, i)];
    om[i][j] = v;
  }
  __syncthreads();
  for (int e2 = tid; e2 < OD * OD; e2 += 256) {
    int i = e2 >> 6, j = e2 & 63;
    float s = 0.f;
    #pragma unroll 8
    for (int k = 0; k < OD; ++k) s = fmaf(om[i][k], om[k][j], s);
    om2[i][j] = s;
  }
  __syncthreads();
  for (int e2 = tid; e2 < OD * OD; e2 += 256) {
    int i = e2 >> 6, j = e2 & 63;
    float s3 = 0.f;
    #pragma unroll 8
    for (int k = 0; k < OD; ++k) s3 = fmaf(om2[i][k], om[k][j], s3);
    float gv = om[i][j] + 0.5f * om2[i][j] + (1.f / 6.f) * s3 + (i == j ? 1.f : 0.f);
    Gout[(size_t)b * OD * OD + e2] = gv;
  }
  if (tid < VD) {
    float a = vib[tid];
    const float* wr = viw + (size_t)tid * DD;
    const float* h = hm + (size_t)b * DD;
    #pragma unroll 8
    for (int k = 0; k < DD; ++k) a = fmaf(wr[k], h[k], a);
    vqi[tid] = a;
  }
  __syncthreads();
  if (tid == 0) {
    float s = 0.f;
    for (int k = 0; k < VD; ++k) s += vqi[k] * vqi[k];
    nv_s = fmaxf(sqrtf(s), 1e-12f);
  }
  __syncthreads();
  {
    const float* cr = cb + (size_t)tid * VD;
    float dot = 0.f, ssq = 0.f;
    #pragma unroll 8
    for (int k = 0; k < VD; ++k) { float cvv = cr[k]; dot = fmaf(cvv, vqi[k], dot); ssq = fmaf(cvv, cvv, ssq); }
    float ncn = fmaxf(sqrtf(ssq), 1e-12f);
    sc[tid] = dot / (nv_s * ncn);
    si[tid] = tid;
  }
  __syncthreads();
  for (int s = 128; s > 0; s >>= 1) {
    if (tid < s) {
      float a = sc[tid], b2 = sc[tid + s];
      int ia = si[tid], ib = si[tid + s];
      if (b2 > a || (b2 == a && ib < ia)) { sc[tid] = b2; si[tid] = ib; }
    }
    __syncthreads();
  }
  const int best = si[0];
  if (tid < VD) cd[tid] = cb[(size_t)best * VD + tid];
  __syncthreads();
  const float omix = omix_p[0], vmix = vmix_p[0];
  for (int e = tid; e < DD; e += 256) {
    float a = vob[e];
    const float* wr = vow + (size_t)e * VD;
    #pragma unroll 8
    for (int k = 0; k < VD; ++k) a = fmaf(cd[k], wr[k], a);
    cvec[(size_t)b * DD + e] = fmaf(omix, oob[e], vmix * a);
  }
}

// ------- Kernel 2c: MTB[b][e][d] = bf16( omix * sum_k G[d][k]*oow[e][k] ) ----
__global__ void k_MTB(const float* __restrict__ G, const float* __restrict__ oow,
                      const float* __restrict__ omix_p, unsigned short* __restrict__ MTB) {
  const int b = blockIdx.y, eb = blockIdx.x * 64, tid = threadIdx.x;
  __shared__ float g[OD][OD + 1];
  __shared__ float wl[64][65];
  for (int e2 = tid; e2 < OD * OD; e2 += 256) g[e2 >> 6][e2 & 63] = G[(size_t)b * OD * OD + e2];
  for (int e2 = tid; e2 < 64 * 64; e2 += 256) wl[e2 >> 6][e2 & 63] = oow[(size_t)(eb + (e2 >> 6)) * 64 + (e2 & 63)];
  __syncthreads();
  const float omix = omix_p[0];
  for (int o = tid; o < 4096; o += 256) {
    int el = o >> 6, d = o & 63;
    float s = 0.f;
    #pragma unroll
    for (int k = 0; k < 64; ++k) s = fmaf(g[d][k], wl[el][k], s);
    MTB[((size_t)b * DD + eb + el) * OD + d] = f2bf(omix * s);
  }
}

// ---------------- Kernel 3: MFMA main pass ----------------
// 512 thr = 8 waves; wave w owns e in [128w,128w+128). B-frags (M as bf16)
// resident in 64 VGPRs -> MFMA forces register residency (no reload games).
// A/B k-map: k=(lane>>4)*8+j used consistently on both operands (any bijection
// is correct if consistent). C/D: col=lane&15, row=(lane>>4)*4+reg (HW-verified).
__global__ __launch_bounds__(512)
void k_mfma(const float* __restrict__ x, const unsigned short* __restrict__ MTB,
            const float* __restrict__ cvec, const float* __restrict__ nw,
            float* __restrict__ out) {
  const int b = blockIdx.y;
  const int Tblk = blockIdx.x * TPB;
  const int tid = threadIdx.x;
  const int w = tid >> 6, lane = tid & 63;
  const int c = lane & 15, g = lane >> 4;
  const int ebase = w * 128;

  __shared__ unsigned short xh[TT][72];  // 144B rows (64 d + 8 pad) -> ~2-way banks
  __shared__ float red[TT][8];
  __shared__ float scl[TT];

  // B fragments: bf[et][ks] = M[d = ks*32 + g*8 + j][e = ebase + et*16 + c]
  bf16x8 bf[8][2];
  {
    const unsigned short* mp = MTB + ((size_t)b * DD + ebase + c) * OD + g * 8;
    #pragma unroll
    for (int et = 0; et < 8; ++et) {
      #pragma unroll
      for (int ks = 0; ks < 2; ++ks)
        bf[et][ks] = *(const bf16x8*)(mp + (size_t)et * 16 * OD + ks * 32);
    }
  }
  float ce_r[8], nw_r[8];
  #pragma unroll
  for (int et = 0; et < 8; ++et) {
    ce_r[et] = cvec[(size_t)b * DD + ebase + et * 16 + c];
    nw_r[et] = nw[ebase + et * 16 + c];
  }

  const size_t xrow = ((size_t)b * LL + Tblk) * DD;

  for (int tt = 0; tt < TPB; tt += TT) {
    // stage x_head tile -> LDS bf16 (threads 0..255)
    if (tid < 256) {
      const int tok = tid >> 4, d0 = (tid & 15) * 4;
      const float4 v = *(const float4*)(x + xrow + (size_t)(tt + tok) * DD + d0);
      unsigned int lo = (unsigned int)f2bf(v.x) | ((unsigned int)f2bf(v.y) << 16);
      unsigned int hi = (unsigned int)f2bf(v.z) | ((unsigned int)f2bf(v.w) << 16);
      *(uint2*)((char*)&xh[0][0] + tok * 144 + d0 * 2) = make_uint2(lo, hi);
    }
    __syncthreads();

    // A frags: row = token = c, k = ks*32 + g*8 + j
    bf16x8 af0 = *(const bf16x8*)((const char*)&xh[0][0] + c * 144 + 0 * 64 + g * 16);
    bf16x8 af1 = *(const bf16x8*)((const char*)&xh[0][0] + c * 144 + 1 * 64 + g * 16);

    f32x4 acc[8];
    #pragma unroll
    for (int et = 0; et < 8; ++et) {
      acc[et] = (f32x4){0.f, 0.f, 0.f, 0.f};
      acc[et] = __builtin_amdgcn_mfma_f32_16x16x32_bf16(af0, bf[et][0], acc[et], 0, 0, 0);
      acc[et] = __builtin_amdgcn_mfma_f32_16x16x32_bf16(af1, bf[et][1], acc[et], 0, 0, 0);
    }

    // epilogue pass 1: y = x + lie + ce; accumulate y^2 per token
    float p[4] = {0.f, 0.f, 0.f, 0.f};
    #pragma unroll
    for (int et = 0; et < 8; ++et) {
      #pragma unroll
      for (int r = 0; r < 4; ++r) {
        const int tok = tt + g * 4 + r;
        const float xv = x[xrow + (size_t)tok * DD + ebase + et * 16 + c];
        const float y = xv + acc[et][r] + ce_r[et];
        acc[et][r] = y;
        p[r] = fmaf(y, y, p[r]);
      }
    }
    // reduce over the 16 e-lanes (c bits)
    #pragma unroll
    for (int mk = 1; mk < 16; mk <<= 1) {
      #pragma unroll
      for (int r = 0; r < 4; ++r) p[r] += __shfl_xor(p[r], mk, 64);
    }
    if (c == 0) {
      #pragma unroll
      for (int r = 0; r < 4; ++r) red[g * 4 + r][w] = p[r];
    }
    __syncthreads();
    if (tid < TT) {
      const float4 s0 = *(const float4*)&red[tid][0];
      const float4 s1 = *(const float4*)&red[tid][4];
      const float s = s0.x + s0.y + s0.z + s0.w + s1.x + s1.y + s1.z + s1.w;
      scl[tid] = rsqrtf(s * (1.f / (float)DD) + 1e-6f);
    }
    __syncthreads();
    float sc_r[4];
    #pragma unroll
    for (int r = 0; r < 4; ++r) sc_r[r] = scl[g * 4 + r];
    // epilogue pass 2: store
    #pragma unroll
    for (int et = 0; et < 8; ++et) {
      #pragma unroll
      for (int r = 0; r < 4; ++r) {
        const int tok = tt + g * 4 + r;
        out[xrow + (size_t)tok * DD + ebase + et * 16 + c] = acc[et][r] * sc_r[r] * nw_r[et];
      }
    }
    // no trailing barrier needed: next iter's xh writes happen after its own
    // stage, which all threads reach only after passing the scl barrier above.
    __syncthreads();
  }
}

extern "C" void kernel_launch(void* const* d_in, const int* in_sizes, int n_in,
                              void* d_out, int out_size, void* d_ws, size_t ws_size,
                              hipStream_t stream) {
  (void)in_sizes; (void)n_in; (void)out_size; (void)ws_size;
  const float* x    = (const float*)d_in[0];
  const float* opw  = (const float*)d_in[1];
  const float* opb  = (const float*)d_in[2];
  const float* oow  = (const float*)d_in[3];
  const float* oob  = (const float*)d_in[4];
  const float* viw  = (const float*)d_in[5];
  const float* vib  = (const float*)d_in[6];
  const float* vow  = (const float*)d_in[7];
  const float* vob  = (const float*)d_in[8];
  const float* cb   = (const float*)d_in[9];
  const float* omix = (const float*)d_in[10];
  const float* vmix = (const float*)d_in[11];
  const float* nw   = (const float*)d_in[12];
  float* out = (float*)d_out;

  float* ws      = (float*)d_ws;
  float* partial = ws;                 // 1048576 floats
  float* hm      = ws + 1048576;       // 16384
  float* params  = ws + 1064960;       // 32256
  float* G       = ws + 1097216;       // 65536
  unsigned short* MTB = (unsigned short*)(ws + 1162752);  // 1M ushort (in old MT slot)
  float* cvec    = ws + 2211328;       // 16384

  k_partial<<<dim3(NCHUNK, BB), 256, 0, stream>>>(x, partial);
  k_mean<<<BB, 256, 0, stream>>>(partial, hm);
  k_params<<<NP / 4, 256, 0, stream>>>(hm, opw, opb, params);
  k_perb<<<BB, 256, 0, stream>>>(hm, params, viw, vib, cb, oob, vow, vob, omix, vmix, G, cvec);
  k_MTB<<<dim3(16, BB), 256, 0, stream>>>(G, oow, omix, MTB);
  k_mfma<<<dim3(LL / TPB, BB), 512, 0, stream>>>(x, MTB, cvec, nw, out);
}

// Round 6
// 273.922 us; speedup vs baseline: 48.6733x; 1.0539x over previous
//
#include <hip/hip_runtime.h>
#include <hip/hip_bf16.h>
#include <math.h>

#define BB 16
#define LL 4096
#define DD 1024
#define OD 64
#define NP 2016
#define NC 256
#define VD 64
#define NCHUNK 64
#define LCH (LL / NCHUNK)
#define TT 16      // tokens per MFMA tile
#define TPB 256    // tokens per block (main kernel)

typedef __attribute__((ext_vector_type(8))) short bf16x8;
typedef __attribute__((ext_vector_type(4))) float f32x4;

__device__ __forceinline__ int triu_idx(int r, int c) {
  return r * 63 - (r * (r - 1)) / 2 + (c - r - 1);
}

__device__ __forceinline__ unsigned short f2bf(float f) {
  unsigned int u = __float_as_uint(f);
  u += 0x7fffu + ((u >> 16) & 1u);
  return (unsigned short)(u >> 16);
}

// ---------------- Kernel 1a: partial sums over L chunks ----------------
__global__ void k_partial(const float* __restrict__ x, float* __restrict__ partial) {
  const int b = blockIdx.y, ch = blockIdx.x, tid = threadIdx.x;
  const float4* xp = (const float4*)(x + ((size_t)b * LL + (size_t)ch * LCH) * DD) + tid;
  float4 s = make_float4(0.f, 0.f, 0.f, 0.f);
  #pragma unroll 8
  for (int l = 0; l < LCH; ++l) {
    float4 v = xp[(size_t)l * (DD / 4)];
    s.x += v.x; s.y += v.y; s.z += v.z; s.w += v.w;
  }
  ((float4*)(partial + ((size_t)(b * NCHUNK + ch)) * DD))[tid] = s;
}

// ---------------- Kernel 1b: finalize mean ----------------
__global__ void k_mean(const float* __restrict__ partial, float* __restrict__ hm) {
  const int b = blockIdx.x, tid = threadIdx.x;
  float4 s = make_float4(0.f, 0.f, 0.f, 0.f);
  for (int c = 0; c < NCHUNK; ++c) {
    float4 v = ((const float4*)(partial + ((size_t)(b * NCHUNK + c)) * DD))[tid];
    s.x += v.x; s.y += v.y; s.z += v.z; s.w += v.w;
  }
  const float inv = 1.0f / (float)LL;
  s.x *= inv; s.y *= inv; s.z *= inv; s.w *= inv;
  ((float4*)(hm + (size_t)b * DD))[tid] = s;
}

// ---------------- Kernel 2a: params = h_mean @ opw.T + opb ----------------
__global__ void k_params(const float* __restrict__ hm, const float* __restrict__ w,
                         const float* __restrict__ bias, float* __restrict__ params) {
  const int wave = threadIdx.x >> 6, lane = threadIdx.x & 63;
  const int p = blockIdx.x * 4 + wave;
  float acc[BB];
  #pragma unroll
  for (int b = 0; b < BB; ++b) acc[b] = 0.f;
  const float* wr = w + (size_t)p * DD;
  for (int i = 0; i < DD; i += 64) {
    const float wv = wr[i + lane];
    #pragma unroll
    for (int b = 0; b < BB; ++b) acc[b] = fmaf(wv, hm[b * DD + i + lane], acc[b]);
  }
  #pragma unroll
  for (int b = 0; b < BB; ++b) {
    float v = acc[b];
    #pragma unroll
    for (int mk = 32; mk; mk >>= 1) v += __shfl_xor(v, mk, 64);
    if (lane == 0) params[(size_t)b * NP + p] = v + bias[p];
  }
}

// ---------------- Kernel 2b: per-batch omega -> G, VQ path, c vector --------
__global__ void k_perb(const float* __restrict__ hm, const float* __restrict__ params,
                       const float* __restrict__ viw, const float* __restrict__ vib,
                       const float* __restrict__ cb,
                       const float* __restrict__ oob, const float* __restrict__ vow,
                       const float* __restrict__ vob,
                       const float* __restrict__ omix_p, const float* __restrict__ vmix_p,
                       float* __restrict__ Gout, float* __restrict__ cvec) {
  const int b = blockIdx.x, tid = threadIdx.x;
  __shared__ float om[OD][OD + 1];
  __shared__ float om2[OD][OD + 1];
  __shared__ float vqi[VD];
  __shared__ float sc[NC];
  __shared__ int si[NC];
  __shared__ float cd[VD];
  __shared__ float nv_s;
  const float* par = params + (size_t)b * NP;

  for (int e2 = tid; e2 < OD * OD; e2 += 256) {
    int i = e2 >> 6, j = e2 & 63;
    float v = 0.f;
    if (i < j) v = par[triu_idx(i, j)];
    else if (i > j) v = -par[triu_idx(j, i)];
    om[i][j] = v;
  }
  __syncthreads();
  for (int e2 = tid; e2 < OD * OD; e2 += 256) {
    int i = e2 >> 6, j = e2 & 63;
    float s = 0.f;
    #pragma unroll 8
    for (int k = 0; k < OD; ++k) s = fmaf(om[i][k], om[k][j], s);
    om2[i][j] = s;
  }
  __syncthreads();
  for (int e2 = tid; e2 < OD * OD; e2 += 256) {
    int i = e2 >> 6, j = e2 & 63;
    float s3 = 0.f;
    #pragma unroll 8
    for (int k = 0; k < OD; ++k) s3 = fmaf(om2[i][k], om[k][j], s3);
    float gv = om[i][j] + 0.5f * om2[i][j] + (1.f / 6.f) * s3 + (i == j ? 1.f : 0.f);
    Gout[(size_t)b * OD * OD + e2] = gv;
  }
  if (tid < VD) {
    float a = vib[tid];
    const float* wr = viw + (size_t)tid * DD;
    const float* h = hm + (size_t)b * DD;
    #pragma unroll 8
    for (int k = 0; k < DD; ++k) a = fmaf(wr[k], h[k], a);
    vqi[tid] = a;
  }
  __syncthreads();
  if (tid == 0) {
    float s = 0.f;
    for (int k = 0; k < VD; ++k) s += vqi[k] * vqi[k];
    nv_s = fmaxf(sqrtf(s), 1e-12f);
  }
  __syncthreads();
  {
    const float* cr = cb + (size_t)tid * VD;
    float dot = 0.f, ssq = 0.f;
    #pragma unroll 8
    for (int k = 0; k < VD; ++k) { float cvv = cr[k]; dot = fmaf(cvv, vqi[k], dot); ssq = fmaf(cvv, cvv, ssq); }
    float ncn = fmaxf(sqrtf(ssq), 1e-12f);
    sc[tid] = dot / (nv_s * ncn);
    si[tid] = tid;
  }
  __syncthreads();
  for (int s = 128; s > 0; s >>= 1) {
    if (tid < s) {
      float a = sc[tid], b2 = sc[tid + s];
      int ia = si[tid], ib = si[tid + s];
      if (b2 > a || (b2 == a && ib < ia)) { sc[tid] = b2; si[tid] = ib; }
    }
    __syncthreads();
  }
  const int best = si[0];
  if (tid < VD) cd[tid] = cb[(size_t)best * VD + tid];
  __syncthreads();
  const float omix = omix_p[0], vmix = vmix_p[0];
  for (int e = tid; e < DD; e += 256) {
    float a = vob[e];
    const float* wr = vow + (size_t)e * VD;
    #pragma unroll 8
    for (int k = 0; k < VD; ++k) a = fmaf(cd[k], wr[k], a);
    cvec[(size_t)b * DD + e] = fmaf(omix, oob[e], vmix * a);
  }
}

// ------- Kernel 2c: MTB[b][e][d] = bf16( omix * sum_k G[d][k]*oow[e][k] ) ----
__global__ void k_MTB(const float* __restrict__ G, const float* __restrict__ oow,
                      const float* __restrict__ omix_p, unsigned short* __restrict__ MTB) {
  const int b = blockIdx.y, eb = blockIdx.x * 64, tid = threadIdx.x;
  __shared__ float g[OD][OD + 1];
  __shared__ float wl[64][65];
  for (int e2 = tid; e2 < OD * OD; e2 += 256) g[e2 >> 6][e2 & 63] = G[(size_t)b * OD * OD + e2];
  for (int e2 = tid; e2 < 64 * 64; e2 += 256) wl[e2 >> 6][e2 & 63] = oow[(size_t)(eb + (e2 >> 6)) * 64 + (e2 & 63)];
  __syncthreads();
  const float omix = omix_p[0];
  for (int o = tid; o < 4096; o += 256) {
    int el = o >> 6, d = o & 63;
    float s = 0.f;
    #pragma unroll
    for (int k = 0; k < 64; ++k) s = fmaf(g[d][k], wl[el][k], s);
    MTB[((size_t)b * DD + eb + el) * OD + d] = f2bf(omix * s);
  }
}

// ---------------- Kernel 3: MFMA main pass (v2) ----------------
// 1024 thr = 16 waves; wave w owns e in [64w, 64w+64) -> bf[4][2] = 32 VGPR,
// total demand ~100 -> fits the 128-VGPR cap a 1024-block imposes -> 16 waves/CU.
// Double-buffered x_head LDS tile + T14 async-stage (next tile's loads issued
// into regs before the epilogue, written to alt buffer after the scl barrier).
// A/B k-map: k = ks*32 + g*8 + j consistently on both operands (any bijection
// correct if consistent). C/D: col=lane&15, row=(lane>>4)*4+reg (HW-verified).
__global__ __launch_bounds__(1024)
void k_mfma(const float* __restrict__ x, const unsigned short* __restrict__ MTB,
            const float* __restrict__ cvec, const float* __restrict__ nw,
            float* __restrict__ out) {
  const int b = blockIdx.y;
  const int Tblk = blockIdx.x * TPB;
  const int tid = threadIdx.x;
  const int w = tid >> 6, lane = tid & 63;
  const int c = lane & 15, g = lane >> 4;
  const int ebase = w * 64;

  __shared__ unsigned short xh[2][TT][72];  // 144B rows: 64 d + 8 pad
  __shared__ float red[TT][16];             // [tok-in-tile][wave]
  __shared__ float scl[TT];

  // B fragments: bf[et][ks] = M[d = ks*32 + g*8 + j][e = ebase + et*16 + c]
  bf16x8 bf[4][2];
  {
    const unsigned short* mp = MTB + ((size_t)b * DD + ebase + c) * OD + g * 8;
    #pragma unroll
    for (int et = 0; et < 4; ++et) {
      #pragma unroll
      for (int ks = 0; ks < 2; ++ks)
        bf[et][ks] = *(const bf16x8*)(mp + (size_t)et * 16 * OD + ks * 32);
    }
  }
  float ce_r[4], nw_r[4];
  #pragma unroll
  for (int et = 0; et < 4; ++et) {
    ce_r[et] = cvec[(size_t)b * DD + ebase + et * 16 + c];
    nw_r[et] = nw[ebase + et * 16 + c];
  }

  const size_t xrow = ((size_t)b * LL + Tblk) * DD;
  const int stok = tid >> 4, sd0 = (tid & 15) * 4;  // staging coords (tid<256)
  const bool stager = (tid < 256);

  // prologue: stage tile 0 into buffer 0
  if (stager) {
    const float4 v = *(const float4*)(x + xrow + (size_t)stok * DD + sd0);
    unsigned int lo = (unsigned int)f2bf(v.x) | ((unsigned int)f2bf(v.y) << 16);
    unsigned int hi = (unsigned int)f2bf(v.z) | ((unsigned int)f2bf(v.w) << 16);
    *(uint2*)((char*)&xh[0][0][0] + stok * 144 + sd0 * 2) = make_uint2(lo, hi);
  }
  __syncthreads();

  int cur = 0;
  for (int tt = 0; tt < TPB; tt += TT) {
    // A frags from xh[cur]: row = token = c, k = ks*32 + g*8 + j
    const char* xbB = (const char*)&xh[cur][0][0];
    bf16x8 af0 = *(const bf16x8*)(xbB + c * 144 + 0 * 64 + g * 16);
    bf16x8 af1 = *(const bf16x8*)(xbB + c * 144 + 1 * 64 + g * 16);

    // T14: issue next tile's global loads now; write to LDS after scl barrier
    float4 nxt;
    const bool havenxt = stager && (tt + TT < TPB);
    if (havenxt)
      nxt = *(const float4*)(x + xrow + (size_t)(tt + TT + stok) * DD + sd0);

    f32x4 acc[4];
    #pragma unroll
    for (int et = 0; et < 4; ++et) {
      acc[et] = (f32x4){0.f, 0.f, 0.f, 0.f};
      acc[et] = __builtin_amdgcn_mfma_f32_16x16x32_bf16(af0, bf[et][0], acc[et], 0, 0, 0);
      acc[et] = __builtin_amdgcn_mfma_f32_16x16x32_bf16(af1, bf[et][1], acc[et], 0, 0, 0);
    }

    // epilogue pass 1: y = x + lie + ce; accumulate y^2 per token
    float p[4] = {0.f, 0.f, 0.f, 0.f};
    #pragma unroll
    for (int et = 0; et < 4; ++et) {
      #pragma unroll
      for (int r = 0; r < 4; ++r) {
        const int tok = tt + g * 4 + r;
        const float xv = x[xrow + (size_t)tok * DD + ebase + et * 16 + c];
        const float y = xv + acc[et][r] + ce_r[et];
        acc[et][r] = y;
        p[r] = fmaf(y, y, p[r]);
      }
    }
    // reduce over the 16 e-lanes (c bits)
    #pragma unroll
    for (int mk = 1; mk < 16; mk <<= 1) {
      #pragma unroll
      for (int r = 0; r < 4; ++r) p[r] += __shfl_xor(p[r], mk, 64);
    }
    if (c == 0) {
      #pragma unroll
      for (int r = 0; r < 4; ++r) red[g * 4 + r][w] = p[r];
    }
    __syncthreads();
    // cross-wave: 256 threads, 16-lane group per token
    if (tid < 256) {
      const int t = tid >> 4;
      float val = red[t][tid & 15];
      #pragma unroll
      for (int mk = 1; mk < 16; mk <<= 1) val += __shfl_xor(val, mk, 64);
      if ((tid & 15) == 0) scl[t] = rsqrtf(val * (1.f / (float)DD) + 1e-6f);
    }
    __syncthreads();
    float sc_r[4];
    #pragma unroll
    for (int r = 0; r < 4; ++r) sc_r[r] = scl[g * 4 + r];
    // epilogue pass 2: store
    #pragma unroll
    for (int et = 0; et < 4; ++et) {
      #pragma unroll
      for (int r = 0; r < 4; ++r) {
        const int tok = tt + g * 4 + r;
        out[xrow + (size_t)tok * DD + ebase + et * 16 + c] = acc[et][r] * sc_r[r] * nw_r[et];
      }
    }
    // write prefetched tile into the alternate buffer
    if (havenxt) {
      unsigned int lo = (unsigned int)f2bf(nxt.x) | ((unsigned int)f2bf(nxt.y) << 16);
      unsigned int hi = (unsigned int)f2bf(nxt.z) | ((unsigned int)f2bf(nxt.w) << 16);
      *(uint2*)((char*)&xh[cur ^ 1][0][0] + stok * 144 + sd0 * 2) = make_uint2(lo, hi);
    }
    __syncthreads();
    cur ^= 1;
  }
}

extern "C" void kernel_launch(void* const* d_in, const int* in_sizes, int n_in,
                              void* d_out, int out_size, void* d_ws, size_t ws_size,
                              hipStream_t stream) {
  (void)in_sizes; (void)n_in; (void)out_size; (void)ws_size;
  const float* x    = (const float*)d_in[0];
  const float* opw  = (const float*)d_in[1];
  const float* opb  = (const float*)d_in[2];
  const float* oow  = (const float*)d_in[3];
  const float* oob  = (const float*)d_in[4];
  const float* viw  = (const float*)d_in[5];
  const float* vib  = (const float*)d_in[6];
  const float* vow  = (const float*)d_in[7];
  const float* vob  = (const float*)d_in[8];
  const float* cb   = (const float*)d_in[9];
  const float* omix = (const float*)d_in[10];
  const float* vmix = (const float*)d_in[11];
  const float* nw   = (const float*)d_in[12];
  float* out = (float*)d_out;

  float* ws      = (float*)d_ws;
  float* partial = ws;                 // 1048576 floats
  float* hm      = ws + 1048576;       // 16384
  float* params  = ws + 1064960;       // 32256
  float* G       = ws + 1097216;       // 65536
  unsigned short* MTB = (unsigned short*)(ws + 1162752);  // 1M ushort
  float* cvec    = ws + 2211328;       // 16384

  k_partial<<<dim3(NCHUNK, BB), 256, 0, stream>>>(x, partial);
  k_mean<<<BB, 256, 0, stream>>>(partial, hm);
  k_params<<<NP / 4, 256, 0, stream>>>(hm, opw, opb, params);
  k_perb<<<BB, 256, 0, stream>>>(hm, params, viw, vib, cb, oob, vow, vob, omix, vmix, G, cvec);
  k_MTB<<<dim3(16, BB), 256, 0, stream>>>(G, oow, omix, MTB);
  k_mfma<<<dim3(LL / TPB, BB), 1024, 0, stream>>>(x, MTB, cvec, nw, out);
}